// Round 3
// baseline (304.461 us; speedup 1.0000x reference)
//
#include <hip/hip_runtime.h>
#include <hip/hip_bf16.h>

// AFCNet: 5 per-batch 1x1-conv GEMMs, B=64, spatial S=64.
// dims: 1024 -> 512 -> 256 -> 128 -> 64 -> 1
// L1,L2: sigmoid + dropout(mask = drop>=0.5, x2). L3,L4: sigmoid. L5: linear.
//
// Design: per-batch GEMM C[o][s] = sum_k W[o][k] * X[k][s]
//   - MFMA 16x16x32 bf16, 3-pass hi/lo split (ahi*bhi + ahi*blo + alo*bhi)
//   - A (=W) fragments loaded DIRECTLY from global (k-contiguous, 2x dwordx4/lane)
//   - B (=X^T) staged per 32-k step in LDS as bf16 hi/lo, row pad 40 elems (80B)
//   - 1-step prefetch (W in regs, X in regs -> LDS double buffer)
//   - WG = 4 waves (256 thr), tile 64 rows x 64 cols; epilogue fuses bias/sigmoid/drop
//   - L4+L5 fused in one per-batch kernel (q4 stays in LDS)
//   - 1D grid, batch in low bits: all M-tiles of a batch land on the same XCD
//     (wgid mod 8 == b mod 8) so X re-reads are L2-local, not L3.
//   - __launch_bounds__(256,4): cap VGPR at 128 -> guaranteed 16 waves/CU.
//     (HBM-latency-bound; need ~9KB/CU outstanding. If counters show spills
//      (scratch traffic, VGPR_Count==128), back off to (256,3).)

typedef __attribute__((ext_vector_type(4))) float f32x4;
typedef __attribute__((ext_vector_type(8))) short short8;
typedef unsigned short ushort_t;
typedef unsigned int uint_t;

__device__ __forceinline__ void split8(const float (&f)[8], short8& hi, short8& lo) {
#pragma unroll
  for (int i = 0; i < 8; i++) {
    uint_t u = __builtin_bit_cast(uint_t, f[i]);
    hi[i] = (short)(u >> 16);
    float hf = __builtin_bit_cast(float, u & 0xffff0000u);
    float l = f[i] - hf;
    lo[i] = (short)(__builtin_bit_cast(uint_t, l) >> 16);
  }
}

// Core K-loop. lds must hold 2(dbuf) x 2(hi/lo) x 2560 ushorts (16B aligned).
// xbase = X + b*Cin*64  (k-major, s contiguous)
// wrow  = W + (b*Cout + (m0 + (lane&15)))*Cin + (lane>>4)*8
__device__ __forceinline__ void run_gemm(const float* __restrict__ xbase,
                                         const float* __restrict__ wrow,
                                         ushort_t* lds, int Cin,
                                         int wave, int lane, f32x4 acc[4]) {
  const int l15 = lane & 15, l4 = lane >> 4;
  const float* xp = xbase + (wave * 8) * 64 + lane;  // 8 k-rows per wave, lane = s

  // ---- prologue: stage step 0 ----
  {
    float x0[8];
#pragma unroll
    for (int i = 0; i < 8; i++) x0[i] = xp[i * 64];
    short8 xh, xl;
    split8(x0, xh, xl);
    *(short8*)(lds + 0 * 2560 + lane * 40 + wave * 8) = xh;  // hi buf0
    *(short8*)(lds + 1 * 2560 + lane * 40 + wave * 8) = xl;  // lo buf0
  }
  f32x4 wv0 = *(const f32x4*)(wrow);
  f32x4 wv1 = *(const f32x4*)(wrow + 4);
  __syncthreads();

  const int ksteps = Cin >> 5;
  int cur = 0;
  for (int ks = 0; ks < ksteps; ks++) {
    const bool more = (ks + 1 < ksteps);
    float xn[8];
    f32x4 wn0, wn1;
    if (more) {  // issue next-step loads early
      const float* xp2 = xp + (size_t)(ks + 1) * 2048;
#pragma unroll
      for (int i = 0; i < 8; i++) xn[i] = xp2[i * 64];
      const float* wp2 = wrow + (ks + 1) * 32;
      wn0 = *(const f32x4*)(wp2);
      wn1 = *(const f32x4*)(wp2 + 4);
    }
    // split current W fragment (8 consecutive k per lane)
    float wf[8];
#pragma unroll
    for (int i = 0; i < 4; i++) { wf[i] = wv0[i]; wf[4 + i] = wv1[i]; }
    short8 ahi, alo;
    split8(wf, ahi, alo);

    ushort_t* bh = lds + (cur * 2 + 0) * 2560;
    ushort_t* bl = lds + (cur * 2 + 1) * 2560;
#pragma unroll
    for (int nf = 0; nf < 4; nf++) {
      int off = (nf * 16 + l15) * 40 + l4 * 8;
      short8 bhf = *(const short8*)(bh + off);
      short8 blf = *(const short8*)(bl + off);
      acc[nf] = __builtin_amdgcn_mfma_f32_16x16x32_bf16(ahi, bhf, acc[nf], 0, 0, 0);
      acc[nf] = __builtin_amdgcn_mfma_f32_16x16x32_bf16(ahi, blf, acc[nf], 0, 0, 0);
      acc[nf] = __builtin_amdgcn_mfma_f32_16x16x32_bf16(alo, bhf, acc[nf], 0, 0, 0);
    }
    if (more) {  // stage next X into alternate buffer
      short8 xh, xl;
      split8(xn, xh, xl);
      *(short8*)(lds + ((cur ^ 1) * 2 + 0) * 2560 + lane * 40 + wave * 8) = xh;
      *(short8*)(lds + ((cur ^ 1) * 2 + 1) * 2560 + lane * 40 + wave * 8) = xl;
      wv0 = wn0;
      wv1 = wn1;
    }
    __syncthreads();
    cur ^= 1;
  }
}

// EPI: 0 = linear, 1 = sigmoid, 2 = sigmoid + dropout
// 1D grid of (ntiles*64); b = wgid & 63 so same-batch tiles share an XCD.
template <int EPI>
__global__ __launch_bounds__(256, 4) void gemm_layer(
    const float* __restrict__ X, const float* __restrict__ W,
    const float* __restrict__ Bias, const float* __restrict__ Drop,
    float* __restrict__ Out, int Cin, int Cout) {
  const int b = blockIdx.x & 63;
  const int mt = blockIdx.x >> 6;
  const int tid = threadIdx.x, wave = tid >> 6, lane = tid & 63;
  const int l15 = lane & 15, l4 = lane >> 4;
  const int m0 = mt * 64 + wave * 16;
  __shared__ __align__(16) ushort_t lds[2 * 2 * 2560];

  const float* xbase = X + (size_t)b * Cin * 64;
  const float* wrow = W + ((size_t)b * Cout + (m0 + l15)) * (size_t)Cin + l4 * 8;

  f32x4 acc[4];
#pragma unroll
  for (int i = 0; i < 4; i++) acc[i] = {0.f, 0.f, 0.f, 0.f};

  run_gemm(xbase, wrow, lds, Cin, wave, lane, acc);

  const size_t obase = (size_t)b * Cout;
#pragma unroll
  for (int r = 0; r < 4; r++) {
    int o = m0 + l4 * 4 + r;  // D row = (lane>>4)*4 + reg
    float bv = Bias[obase + o];
#pragma unroll
    for (int nf = 0; nf < 4; nf++) {
      int s = nf * 16 + l15;  // D col = lane&15
      float v = acc[nf][r] + bv;
      if (EPI >= 1) v = 1.0f / (1.0f + __expf(-v));
      if (EPI == 2) {
        float dv = Drop[(obase + o) * 64 + s];
        v = (dv >= 0.5f) ? 2.0f * v : 0.0f;
      }
      Out[(obase + o) * 64 + s] = v;
    }
  }
}

// Fused layer4 (64x128 GEMM + sigmoid -> LDS) + layer5 (1x64 dot + bias)
__global__ __launch_bounds__(256, 4) void l45_kernel(
    const float* __restrict__ Q3, const float* __restrict__ W4,
    const float* __restrict__ B4f, const float* __restrict__ W5,
    const float* __restrict__ B5f, float* __restrict__ Out) {
  const int b = blockIdx.x;
  const int tid = threadIdx.x, wave = tid >> 6, lane = tid & 63;
  const int l15 = lane & 15, l4 = lane >> 4;
  const int m0 = wave * 16;
  __shared__ __align__(16) ushort_t lds[2 * 2 * 2560];
  __shared__ float q4s[64][64];
  __shared__ float part[4][64];

  const float* xbase = Q3 + (size_t)b * 128 * 64;
  const float* wrow = W4 + ((size_t)b * 64 + (m0 + l15)) * 128 + l4 * 8;

  f32x4 acc[4];
#pragma unroll
  for (int i = 0; i < 4; i++) acc[i] = {0.f, 0.f, 0.f, 0.f};

  run_gemm(xbase, wrow, lds, 128, wave, lane, acc);

#pragma unroll
  for (int r = 0; r < 4; r++) {
    int o = m0 + l4 * 4 + r;
    float bv = B4f[b * 64 + o];
#pragma unroll
    for (int nf = 0; nf < 4; nf++) {
      float v = acc[nf][r] + bv;
      v = 1.0f / (1.0f + __expf(-v));
      q4s[o][nf * 16 + l15] = v;
    }
  }
  __syncthreads();

  // layer5: 64-length dot per spatial s, split across 4 waves (16 k each)
  {
    float a = 0.f;
#pragma unroll
    for (int k = wave * 16; k < wave * 16 + 16; k++)
      a += W5[b * 64 + k] * q4s[k][lane];
    part[wave][lane] = a;
  }
  __syncthreads();
  if (wave == 0) {
    Out[b * 64 + lane] =
        part[0][lane] + part[1][lane] + part[2][lane] + part[3][lane] + B5f[b];
  }
}

extern "C" void kernel_launch(void* const* d_in, const int* in_sizes, int n_in,
                              void* d_out, int out_size, void* d_ws, size_t ws_size,
                              hipStream_t stream) {
  const float* x = (const float*)d_in[0];
  const float* w1 = (const float*)d_in[1];
  const float* b1 = (const float*)d_in[2];
  const float* w2 = (const float*)d_in[3];
  const float* b2 = (const float*)d_in[4];
  const float* w3 = (const float*)d_in[5];
  const float* b3 = (const float*)d_in[6];
  const float* w4 = (const float*)d_in[7];
  const float* b4 = (const float*)d_in[8];
  const float* w5 = (const float*)d_in[9];
  const float* b5 = (const float*)d_in[10];
  const float* drop1 = (const float*)d_in[11];
  const float* drop2 = (const float*)d_in[12];
  float* out = (float*)d_out;

  float* q1 = (float*)d_ws;                   // 64*512*64 f32 = 8 MB
  float* q2 = q1 + (size_t)64 * 512 * 64;     // 64*256*64 f32 = 4 MB
  float* q3 = q2 + (size_t)64 * 256 * 64;     // 64*128*64 f32 = 2 MB

  // 1D grids, batch in low 6 bits (wgid mod 8 == b mod 8 -> same XCD per batch)
  gemm_layer<2><<<dim3(8 * 64), 256, 0, stream>>>(x, w1, b1, drop1, q1, 1024, 512);
  gemm_layer<2><<<dim3(4 * 64), 256, 0, stream>>>(q1, w2, b2, drop2, q2, 512, 256);
  gemm_layer<1><<<dim3(2 * 64), 256, 0, stream>>>(q2, w3, b3, nullptr, q3, 256, 128);
  l45_kernel<<<dim3(64), 256, 0, stream>>>(q3, w4, b4, w5, b5, out);
}

// Round 7
// 295.480 us; speedup vs baseline: 1.0304x; 1.0304x over previous
//
#include <hip/hip_runtime.h>
#include <hip/hip_bf16.h>

// AFCNet: 5 per-batch 1x1-conv GEMMs, B=64, spatial S=64.
// dims: 1024 -> 512 -> 256 -> 128 -> 64 -> 1
// L1,L2: sigmoid + dropout(mask = drop>=0.5, x2). L3,L4: sigmoid. L5: linear.
//
// Round-4..7 design (from measured VGPR=40 / 1.1 TB/s / 79us on L1):
//   - sched_barrier(0) fences pin the software pipeline (compiler had sunk
//     the prefetch loads to their use point -> serial latency per K-step).
//   - W prefetch deepened to 2 K-steps (dominant 134 MB stream).
//   - __launch_bounds__(256,2): occupancy is grid-limited (2 blocks/CU);
//     the old (256,4)=128-VGPR cap invited de-pipelining/spilling.
//   - L3+L4+L5 fused into one per-batch kernel (q3,q4 live in LDS as f32;
//     read-time bf16 hi/lo split keeps numerics identical).

typedef __attribute__((ext_vector_type(4))) float f32x4;
typedef __attribute__((ext_vector_type(8))) short short8;
typedef unsigned short ushort_t;
typedef unsigned int uint_t;

__device__ __forceinline__ void split8(const float (&f)[8], short8& hi, short8& lo) {
#pragma unroll
  for (int i = 0; i < 8; i++) {
    uint_t u = __builtin_bit_cast(uint_t, f[i]);
    hi[i] = (short)(u >> 16);
    float hf = __builtin_bit_cast(float, u & 0xffff0000u);
    float l = f[i] - hf;
    lo[i] = (short)(__builtin_bit_cast(uint_t, l) >> 16);
  }
}

#define MFMA_BF16 __builtin_amdgcn_mfma_f32_16x16x32_bf16

// Core K-loop. lds: 2(dbuf) x 2(hi/lo) x 2560 ushorts (16B aligned).
// xbase = X + b*Cin*64 (k-major, s contiguous)
// wrow  = W + (b*Cout + (m0 + l15))*Cin + l4*8
__device__ __forceinline__ void run_gemm(const float* __restrict__ xbase,
                                         const float* __restrict__ wrow,
                                         ushort_t* lds, int Cin,
                                         int wave, int lane, f32x4 acc[4]) {
  const int l15 = lane & 15, l4 = lane >> 4;
  const float* xp = xbase + (wave * 8) * 64 + lane;  // 8 k-rows per wave, lane = s

  // ---- prologue: stage X step 0; W 2-deep prefetch ----
  {
    float x0[8];
#pragma unroll
    for (int i = 0; i < 8; i++) x0[i] = xp[i * 64];
    short8 xh, xl;
    split8(x0, xh, xl);
    *(short8*)(lds + 0 * 2560 + lane * 40 + wave * 8) = xh;
    *(short8*)(lds + 1 * 2560 + lane * 40 + wave * 8) = xl;
  }
  const int ksteps = Cin >> 5;
  f32x4 wA0 = *(const f32x4*)(wrow);
  f32x4 wA1 = *(const f32x4*)(wrow + 4);
  f32x4 wB0{}, wB1{};
  if (ksteps > 1) {
    wB0 = *(const f32x4*)(wrow + 32);
    wB1 = *(const f32x4*)(wrow + 36);
  }
  __syncthreads();

  int cur = 0;
  for (int ks = 0; ks < ksteps; ks++) {
    const bool morex = (ks + 1 < ksteps);
    const bool morew = (ks + 2 < ksteps);
    float xn[8];
    f32x4 wn0{}, wn1{};
    if (morex) {  // issue next-step X loads early
      const float* xp2 = xp + (size_t)(ks + 1) * 2048;
#pragma unroll
      for (int i = 0; i < 8; i++) xn[i] = xp2[i * 64];
    }
    if (morew) {  // issue W loads 2 steps ahead
      const float* wp2 = wrow + (ks + 2) * 32;
      wn0 = *(const f32x4*)(wp2);
      wn1 = *(const f32x4*)(wp2 + 4);
    }
    __builtin_amdgcn_sched_barrier(0);  // loads stay ABOVE the compute

    float wf[8];
#pragma unroll
    for (int i = 0; i < 4; i++) { wf[i] = wA0[i]; wf[4 + i] = wA1[i]; }
    short8 ahi, alo;
    split8(wf, ahi, alo);

    ushort_t* bh = lds + (cur * 2 + 0) * 2560;
    ushort_t* bl = lds + (cur * 2 + 1) * 2560;
#pragma unroll
    for (int nf = 0; nf < 4; nf++) {
      int off = (nf * 16 + l15) * 40 + l4 * 8;
      short8 bhf = *(const short8*)(bh + off);
      short8 blf = *(const short8*)(bl + off);
      acc[nf] = MFMA_BF16(ahi, bhf, acc[nf], 0, 0, 0);
      acc[nf] = MFMA_BF16(ahi, blf, acc[nf], 0, 0, 0);
      acc[nf] = MFMA_BF16(alo, bhf, acc[nf], 0, 0, 0);
    }
    __builtin_amdgcn_sched_barrier(0);  // consume of prefetch stays BELOW

    if (morex) {
      short8 xh, xl;
      split8(xn, xh, xl);
      *(short8*)(lds + ((cur ^ 1) * 2 + 0) * 2560 + lane * 40 + wave * 8) = xh;
      *(short8*)(lds + ((cur ^ 1) * 2 + 1) * 2560 + lane * 40 + wave * 8) = xl;
    }
    wA0 = wB0; wA1 = wB1; wB0 = wn0; wB1 = wn1;  // shift W pipeline
    __syncthreads();
    cur ^= 1;
  }
}

// EPI: 1 = sigmoid, 2 = sigmoid + dropout
// 1D grid (ntiles*64); b = wgid & 63 so same-batch tiles share an XCD.
template <int EPI>
__global__ __launch_bounds__(256, 2) void gemm_layer(
    const float* __restrict__ X, const float* __restrict__ W,
    const float* __restrict__ Bias, const float* __restrict__ Drop,
    float* __restrict__ Out, int Cin, int Cout) {
  const int b = blockIdx.x & 63;
  const int mt = blockIdx.x >> 6;
  const int tid = threadIdx.x, wave = tid >> 6, lane = tid & 63;
  const int l15 = lane & 15, l4 = lane >> 4;
  const int m0 = mt * 64 + wave * 16;
  __shared__ __align__(16) ushort_t lds[2 * 2 * 2560];

  const float* xbase = X + (size_t)b * Cin * 64;
  const float* wrow = W + ((size_t)b * Cout + (m0 + l15)) * (size_t)Cin + l4 * 8;

  f32x4 acc[4];
#pragma unroll
  for (int i = 0; i < 4; i++) acc[i] = {0.f, 0.f, 0.f, 0.f};

  run_gemm(xbase, wrow, lds, Cin, wave, lane, acc);

  const size_t obase = (size_t)b * Cout;
#pragma unroll
  for (int r = 0; r < 4; r++) {
    int o = m0 + l4 * 4 + r;  // D row = (lane>>4)*4 + reg
    float bv = Bias[obase + o];
#pragma unroll
    for (int nf = 0; nf < 4; nf++) {
      int s = nf * 16 + l15;  // D col = lane&15
      float v = acc[nf][r] + bv;
      v = 1.0f / (1.0f + __expf(-v));
      if (EPI == 2) {
        float dv = Drop[(obase + o) * 64 + s];
        v = (dv >= 0.5f) ? 2.0f * v : 0.0f;
      }
      Out[(obase + o) * 64 + s] = v;
    }
  }
}

// Fused L3 (128x256 GEMM+sigmoid -> LDS q3) + L4 (64x128 GEMM+sigmoid -> LDS q4)
// + L5 (1x64 dot + bias). One WG per batch.
__global__ __launch_bounds__(256, 2) void l345_kernel(
    const float* __restrict__ Q2, const float* __restrict__ W3,
    const float* __restrict__ B3, const float* __restrict__ W4,
    const float* __restrict__ B4, const float* __restrict__ W5,
    const float* __restrict__ B5, float* __restrict__ Out) {
  const int b = blockIdx.x;
  const int tid = threadIdx.x, wave = tid >> 6, lane = tid & 63;
  const int l15 = lane & 15, l4 = lane >> 4;

  __shared__ __align__(16) ushort_t lds[2 * 2 * 2560];  // 20 KB staging
  __shared__ __align__(16) float q3s[64][132];          // [s][o3]
  __shared__ __align__(16) float q4s[64][68];           // [s][o4]
  __shared__ float part[4][64];

  // ================= L3: q3 = sigmoid(W3·q2 + b3) =================
  const float* xbase = Q2 + (size_t)b * 256 * 64;
  const float* wrow0 = W3 + ((size_t)b * 128 + wave * 32 + l15) * 256 + l4 * 8;
  const float* wrow1 = wrow0 + 16 * 256;
  const float* xp = xbase + (wave * 8) * 64 + lane;

  f32x4 acc3[2][4];
#pragma unroll
  for (int m = 0; m < 2; m++)
#pragma unroll
    for (int i = 0; i < 4; i++) acc3[m][i] = {0.f, 0.f, 0.f, 0.f};

  {
    float x0[8];
#pragma unroll
    for (int i = 0; i < 8; i++) x0[i] = xp[i * 64];
    short8 xh, xl;
    split8(x0, xh, xl);
    *(short8*)(lds + 0 * 2560 + lane * 40 + wave * 8) = xh;
    *(short8*)(lds + 1 * 2560 + lane * 40 + wave * 8) = xl;
  }
  f32x4 wA00 = *(const f32x4*)(wrow0), wA01 = *(const f32x4*)(wrow0 + 4);
  f32x4 wA10 = *(const f32x4*)(wrow1), wA11 = *(const f32x4*)(wrow1 + 4);
  f32x4 wB00 = *(const f32x4*)(wrow0 + 32), wB01 = *(const f32x4*)(wrow0 + 36);
  f32x4 wB10 = *(const f32x4*)(wrow1 + 32), wB11 = *(const f32x4*)(wrow1 + 36);
  __syncthreads();

  int cur = 0;
  for (int ks = 0; ks < 8; ks++) {
    const bool morex = (ks + 1 < 8), morew = (ks + 2 < 8);
    float xn[8];
    f32x4 wn00{}, wn01{}, wn10{}, wn11{};
    if (morex) {
      const float* xp2 = xp + (size_t)(ks + 1) * 2048;
#pragma unroll
      for (int i = 0; i < 8; i++) xn[i] = xp2[i * 64];
    }
    if (morew) {
      const float* p0 = wrow0 + (ks + 2) * 32;
      const float* p1 = wrow1 + (ks + 2) * 32;
      wn00 = *(const f32x4*)(p0); wn01 = *(const f32x4*)(p0 + 4);
      wn10 = *(const f32x4*)(p1); wn11 = *(const f32x4*)(p1 + 4);
    }
    __builtin_amdgcn_sched_barrier(0);

    float wf0[8], wf1[8];
#pragma unroll
    for (int i = 0; i < 4; i++) {
      wf0[i] = wA00[i]; wf0[4 + i] = wA01[i];
      wf1[i] = wA10[i]; wf1[4 + i] = wA11[i];
    }
    short8 a0h, a0l, a1h, a1l;
    split8(wf0, a0h, a0l);
    split8(wf1, a1h, a1l);

    ushort_t* bh = lds + (cur * 2 + 0) * 2560;
    ushort_t* bl = lds + (cur * 2 + 1) * 2560;
#pragma unroll
    for (int nf = 0; nf < 4; nf++) {
      int off = (nf * 16 + l15) * 40 + l4 * 8;
      short8 bhf = *(const short8*)(bh + off);
      short8 blf = *(const short8*)(bl + off);
      acc3[0][nf] = MFMA_BF16(a0h, bhf, acc3[0][nf], 0, 0, 0);
      acc3[0][nf] = MFMA_BF16(a0h, blf, acc3[0][nf], 0, 0, 0);
      acc3[0][nf] = MFMA_BF16(a0l, bhf, acc3[0][nf], 0, 0, 0);
      acc3[1][nf] = MFMA_BF16(a1h, bhf, acc3[1][nf], 0, 0, 0);
      acc3[1][nf] = MFMA_BF16(a1h, blf, acc3[1][nf], 0, 0, 0);
      acc3[1][nf] = MFMA_BF16(a1l, bhf, acc3[1][nf], 0, 0, 0);
    }
    __builtin_amdgcn_sched_barrier(0);

    if (morex) {
      short8 xh, xl;
      split8(xn, xh, xl);
      *(short8*)(lds + ((cur ^ 1) * 2 + 0) * 2560 + lane * 40 + wave * 8) = xh;
      *(short8*)(lds + ((cur ^ 1) * 2 + 1) * 2560 + lane * 40 + wave * 8) = xl;
    }
    wA00 = wB00; wA01 = wB01; wA10 = wB10; wA11 = wB11;
    wB00 = wn00; wB01 = wn01; wB10 = wn10; wB11 = wn11;
    __syncthreads();
    cur ^= 1;
  }

  // Prefetch this wave's full W4 row (hides under L3 epilogue + barrier).
  const float* w4row = W4 + ((size_t)b * 64 + wave * 16 + l15) * 128 + l4 * 8;
  f32x4 w4r[8];
#pragma unroll
  for (int ss = 0; ss < 4; ss++) {
    w4r[2 * ss] = *(const f32x4*)(w4row + ss * 32);
    w4r[2 * ss + 1] = *(const f32x4*)(w4row + ss * 32 + 4);
  }

  // L3 epilogue -> q3s[s][o3] (f32, exact)
#pragma unroll
  for (int mf = 0; mf < 2; mf++) {
    int o0 = wave * 32 + mf * 16 + l4 * 4;
#pragma unroll
    for (int nf = 0; nf < 4; nf++) {
      int s = nf * 16 + l15;
      f32x4 v;
#pragma unroll
      for (int r = 0; r < 4; r++) {
        float t = acc3[mf][nf][r] + B3[(size_t)b * 128 + o0 + r];
        v[r] = 1.0f / (1.0f + __expf(-t));
      }
      *(f32x4*)&q3s[s][o0] = v;
    }
  }
  __syncthreads();

  // ================= L4: q4 = sigmoid(W4·q3 + b4) =================
  f32x4 acc4[4];
#pragma unroll
  for (int i = 0; i < 4; i++) acc4[i] = {0.f, 0.f, 0.f, 0.f};

#pragma unroll
  for (int ks = 0; ks < 4; ks++) {
    float wf[8];
#pragma unroll
    for (int i = 0; i < 4; i++) { wf[i] = w4r[2 * ks][i]; wf[4 + i] = w4r[2 * ks + 1][i]; }
    short8 ah, al;
    split8(wf, ah, al);
#pragma unroll
    for (int nf = 0; nf < 4; nf++) {
      int s = nf * 16 + l15;
      float bf[8];
      *(f32x4*)&bf[0] = *(const f32x4*)&q3s[s][ks * 32 + l4 * 8];
      *(f32x4*)&bf[4] = *(const f32x4*)&q3s[s][ks * 32 + l4 * 8 + 4];
      short8 bhf, blf;
      split8(bf, bhf, blf);
      acc4[nf] = MFMA_BF16(ah, bhf, acc4[nf], 0, 0, 0);
      acc4[nf] = MFMA_BF16(ah, blf, acc4[nf], 0, 0, 0);
      acc4[nf] = MFMA_BF16(al, bhf, acc4[nf], 0, 0, 0);
    }
  }
  {
    int o0 = wave * 16 + l4 * 4;
#pragma unroll
    for (int nf = 0; nf < 4; nf++) {
      int s = nf * 16 + l15;
      f32x4 v;
#pragma unroll
      for (int r = 0; r < 4; r++) {
        float t = acc4[nf][r] + B4[(size_t)b * 64 + o0 + r];
        v[r] = 1.0f / (1.0f + __expf(-t));
      }
      *(f32x4*)&q4s[s][o0] = v;
    }
  }
  __syncthreads();

  // ================= L5: out[s] = sum_k W5[k]*q4[k][s] + b5 =================
  {
    float a = 0.f;
#pragma unroll
    for (int k = wave * 16; k < wave * 16 + 16; k++)
      a += W5[(size_t)b * 64 + k] * q4s[lane][k];
    part[wave][lane] = a;
  }
  __syncthreads();
  if (wave == 0) {
    Out[(size_t)b * 64 + lane] =
        part[0][lane] + part[1][lane] + part[2][lane] + part[3][lane] + B5[b];
  }
}

extern "C" void kernel_launch(void* const* d_in, const int* in_sizes, int n_in,
                              void* d_out, int out_size, void* d_ws, size_t ws_size,
                              hipStream_t stream) {
  const float* x = (const float*)d_in[0];
  const float* w1 = (const float*)d_in[1];
  const float* b1 = (const float*)d_in[2];
  const float* w2 = (const float*)d_in[3];
  const float* b2 = (const float*)d_in[4];
  const float* w3 = (const float*)d_in[5];
  const float* b3 = (const float*)d_in[6];
  const float* w4 = (const float*)d_in[7];
  const float* b4 = (const float*)d_in[8];
  const float* w5 = (const float*)d_in[9];
  const float* b5 = (const float*)d_in[10];
  const float* drop1 = (const float*)d_in[11];
  const float* drop2 = (const float*)d_in[12];
  float* out = (float*)d_out;

  float* q1 = (float*)d_ws;                // 64*512*64 f32 = 8 MB
  float* q2 = q1 + (size_t)64 * 512 * 64;  // 64*256*64 f32 = 4 MB

  // 1D grids, batch in low 6 bits (wgid mod 8 == b mod 8 -> same XCD per batch)
  gemm_layer<2><<<dim3(8 * 64), 256, 0, stream>>>(x, w1, b1, drop1, q1, 1024, 512);
  gemm_layer<2><<<dim3(4 * 64), 256, 0, stream>>>(q1, w2, b2, drop2, q2, 512, 256);
  l345_kernel<<<dim3(64), 256, 0, stream>>>(q2, w3, b3, w4, b4, w5, b5, out);
}